// Round 17
// baseline (116.845 us; speedup 1.0000x reference)
//
#include <hip/hip_runtime.h>

#define DIN 1024
#define DC 64
#define KC 4096

typedef _Float16 f16x8 __attribute__((ext_vector_type(8)));
typedef _Float16 f16x4 __attribute__((ext_vector_type(4)));
typedef float f32x4 __attribute__((ext_vector_type(4)));

__device__ __forceinline__ void gll16(const void* g, void* l) {
    __builtin_amdgcn_global_load_lds(
        (const __attribute__((address_space(1))) unsigned int*)g,
        (__attribute__((address_space(3))) unsigned int*)l, 16, 0, 0);
}

// ---------------------------------------------------------------------------
// Prep.  b<1024: Ee [4096][64] f16 + sqr fp32 + zero counts.
//        b<1040: W_send -> Wh [64 col][1024 k] f16 (transposed).
//        b<1056: W_recv -> WrT [1024 col][64 k] f16 (transposed).
__global__ __launch_bounds__(256) void k_prep(const float* __restrict__ emb,
                                              const float* __restrict__ Ws,
                                              const float* __restrict__ Wr,
                                              _Float16* __restrict__ Ee,
                                              float* __restrict__ sqr,
                                              _Float16* __restrict__ Wh,
                                              _Float16* __restrict__ WrT,
                                              int* __restrict__ counts) {
    int b = blockIdx.x;
    int tid = threadIdx.x;
    if (b < 1024) {
        int code = b * 4 + (tid >> 6);
        int lane = tid & 63;
        float v = emb[(size_t)code * DC + lane];
        Ee[(size_t)code * 64 + lane] = (_Float16)v;
        float s = v * v;
        #pragma unroll
        for (int m = 1; m < 64; m <<= 1) s += __shfl_xor(s, m);
        if (lane == 0) sqr[code] = s;
        if (tid < 4) counts[b * 4 + tid] = 0;
        return;
    }
    if (b < 1040) {
        int k0 = (b - 1024) * 64;
        #pragma unroll
        for (int it = 0; it < 16; ++it) {
            int q = it * 256 + tid;          // 4096 = 64c x 64k
            int c = q >> 6, kl = q & 63;
            float v = Ws[(size_t)(k0 + kl) * 64 + c];
            Wh[(size_t)c * 1024 + k0 + kl] = (_Float16)v;
        }
        return;
    }
    // WrT[col][k] = W_recv[k][col], coalesced reads
    int b2 = b - 1040;
    #pragma unroll
    for (int it = 0; it < 16; ++it) {
        int k = it * 4 + (tid >> 6);
        int rr = b2 * 64 + (tid & 63);
        WrT[(size_t)rr * 64 + k] = (_Float16)Wr[(size_t)k * 1024 + rr];
    }
}

// ---------------------------------------------------------------------------
// Fused send + score.  256 thr, 64 rows/block, grid 512 (R11 geometry).
// Send: z = in @ W_send + b (f16 MFMA, 16 K-steps, dbuf 2x16KB @[0,32K)).
// Zt: acc+bias -> f16 -> swizzled Zt[64][128B] @16384 (dead send buf1).
// Score: BARRIER-FREE — E-fragments loaded directly global(L2)->registers
//   (Ee is 512 KB, L2-resident; no LDS staging, no __syncthreads, 64 chunks
//   software-prefetched 1 ahead).  Argmin + ||z||^2 + loss fused as before.
__global__ __launch_bounds__(256) void k_main(const float* __restrict__ in,
                                              const _Float16* __restrict__ Wh,
                                              const float* __restrict__ bs,
                                              const _Float16* __restrict__ Ee,
                                              const float* __restrict__ sqr,
                                              int* __restrict__ idx,
                                              float* __restrict__ out_idx,
                                              int* __restrict__ counts,
                                              float* __restrict__ lpart) {
    __shared__ char smem[32768];
    const int tid = threadIdx.x;
    const int row0 = blockIdx.x * 64;
    const int wid = tid >> 6, lane = tid & 63;
    const int c15 = lane & 15, g = lane >> 4;
    const int g16 = g * 16;
    const int wm = wid >> 1, wn = wid & 1;
    const f32x4 zz4 = {0.f, 0.f, 0.f, 0.f};

    // ================= send phase =================
    f32x4 acc[2][2];
    #pragma unroll
    for (int mf = 0; mf < 2; ++mf)
        #pragma unroll
        for (int nf = 0; nf < 2; ++nf) acc[mf][nf] = zz4;

    int abyte[2], aswz[2], bbyte[2], bswz[2];
    #pragma unroll
    for (int mf = 0; mf < 2; ++mf) {
        int r = wm * 32 + mf * 16 + c15;
        abyte[mf] = r * 128; aswz[mf] = (r & 7) << 4;
    }
    #pragma unroll
    for (int nf = 0; nf < 2; ++nf) {
        int c = wn * 32 + nf * 16 + c15;
        bbyte[nf] = c * 128; bswz[nf] = (c & 7) << 4;
    }

    auto stageB = [&](int buf, int s) {      // Wh k-chunk: 64 cols x 128 B
        char* dst = smem + buf * 16384 + 8192;
        #pragma unroll
        for (int r = 0; r < 2; ++r) {
            int p = r * 4096 + wid * 1024 + lane * 16;
            int row = p >> 7, off = p & 127;
            int soff = off ^ ((row & 7) << 4);
            gll16((const char*)Wh + (size_t)row * 2048 + s * 128 + soff,
                  dst + p);
        }
    };
    auto loadA = [&](int s, float4* a) {
        #pragma unroll
        for (int it = 0; it < 4; ++it) {
            int q = it * 256 + tid;
            int r = q >> 4, c4 = q & 15;
            a[it] = *(const float4*)&in[(size_t)(row0 + r) * DIN + s * 64 + c4 * 4];
        }
    };
    auto writeA = [&](int buf, const float4* a) {
        char* Ah = smem + buf * 16384;
        #pragma unroll
        for (int it = 0; it < 4; ++it) {
            int q = it * 256 + tid;
            int r = q >> 4, c4 = q & 15;
            float v[4] = {a[it].x, a[it].y, a[it].z, a[it].w};
            f16x4 h;
            #pragma unroll
            for (int j = 0; j < 4; ++j) h[j] = (_Float16)v[j];
            int o = r * 128 + ((c4 * 8) ^ ((r & 7) << 4));
            *(f16x4*)(Ah + o) = h;
        }
    };
    auto computeS = [&](int buf) {
        const char* Ah = smem + buf * 16384;
        const char* Bh = Ah + 8192;
        #pragma unroll
        for (int ks = 0; ks < 2; ++ks) {
            int koff = ks * 64 + g16;
            f16x8 bh[2];
            #pragma unroll
            for (int nf = 0; nf < 2; ++nf)
                bh[nf] = *(const f16x8*)(Bh + bbyte[nf] + (koff ^ bswz[nf]));
            #pragma unroll
            for (int mf = 0; mf < 2; ++mf) {
                f16x8 ah = *(const f16x8*)(Ah + abyte[mf] + (koff ^ aswz[mf]));
                #pragma unroll
                for (int nf = 0; nf < 2; ++nf)
                    acc[mf][nf] = __builtin_amdgcn_mfma_f32_16x16x32_f16(
                        ah, bh[nf], acc[mf][nf], 0, 0, 0);
            }
        }
    };

    {
        float4 a0[4];
        loadA(0, a0);
        stageB(0, 0);
        writeA(0, a0);
    }
    __syncthreads();
    for (int s = 0; s < 16; ++s) {
        int c = s & 1;
        float4 an[4];
        if (s < 15) {
            loadA(s + 1, an);
            stageB(c ^ 1, s + 1);
        }
        computeS(c);
        if (s < 15) writeA(c ^ 1, an);
        __syncthreads();
    }

    // ================= z -> Zt (LDS, f16, swizzled) =================
    char* Zt = smem + 16384;
    #pragma unroll
    for (int nf = 0; nf < 2; ++nf) {
        int k = wn * 32 + nf * 16 + c15;
        float bias = bs[k];
        #pragma unroll
        for (int mf = 0; mf < 2; ++mf)
            #pragma unroll
            for (int r2 = 0; r2 < 4; ++r2) {
                int row = wm * 32 + mf * 16 + g * 4 + r2;
                *(_Float16*)(Zt + row * 128 + ((k * 2) ^ ((row & 7) << 4)))
                    = (_Float16)(acc[mf][nf][r2] + bias);
            }
    }
    __syncthreads();   // Zt visible

    // ================= score phase (barrier-free, E from L2) =================
    f16x8 zfh[2][2];
    #pragma unroll
    for (int nf = 0; nf < 2; ++nf) {
        int zr = wn * 32 + nf * 16 + c15;
        int sw = (zr & 7) << 4;
        #pragma unroll
        for (int j = 0; j < 2; ++j)
            zfh[j][nf] = *(const f16x8*)(Zt + zr * 128 + ((j * 64 + g16) ^ sw));
    }

    // per-lane E base: row = wm*32 + c15 (mf adds 16 rows), elems j*32 + g*8
    const _Float16* ebase = Ee + ((size_t)(wm * 32 + c15)) * 64 + g * 8;

    float bv[2];
    int   bi[2];
    #pragma unroll
    for (int nf = 0; nf < 2; ++nf) { bv[nf] = 3.402823466e38f; bi[nf] = 0; }

    f16x8 af[2][2];          // [mf][j] current chunk
    f32x4 sqv[2];
    #pragma unroll
    for (int mf = 0; mf < 2; ++mf) {
        #pragma unroll
        for (int j = 0; j < 2; ++j)
            af[mf][j] = *(const f16x8*)(ebase + mf * 1024 + j * 32);
        sqv[mf] = *(const f32x4*)(sqr + wm * 32 + mf * 16 + g * 4);
    }

    for (int ch = 0; ch < 64; ++ch) {
        f16x8 an2[2][2];
        f32x4 sqn[2];
        if (ch < 63) {
            const _Float16* eb = ebase + (size_t)(ch + 1) * 4096;
            #pragma unroll
            for (int mf = 0; mf < 2; ++mf) {
                #pragma unroll
                for (int j = 0; j < 2; ++j)
                    an2[mf][j] = *(const f16x8*)(eb + mf * 1024 + j * 32);
                sqn[mf] = *(const f32x4*)(sqr + (ch + 1) * 64 + wm * 32
                                          + mf * 16 + g * 4);
            }
        }

        f32x4 sacc[2][2];
        #pragma unroll
        for (int j = 0; j < 2; ++j)
            #pragma unroll
            for (int mf = 0; mf < 2; ++mf)
                #pragma unroll
                for (int nf = 0; nf < 2; ++nf)
                    sacc[mf][nf] = __builtin_amdgcn_mfma_f32_16x16x32_f16(
                        af[mf][j], zfh[j][nf],
                        j == 0 ? zz4 : sacc[mf][nf], 0, 0, 0);

        #pragma unroll
        for (int nf = 0; nf < 2; ++nf) {
            #pragma unroll
            for (int mf = 0; mf < 2; ++mf) {
                f32x4 v = sqv[mf] - sacc[mf][nf] * 2.0f;
                #pragma unroll
                for (int r2 = 0; r2 < 4; ++r2) {
                    if (v[r2] < bv[nf]) {
                        bv[nf] = v[r2];
                        bi[nf] = ch * 64 + wm * 32 + mf * 16 + g * 4 + r2;
                    }
                }
            }
        }

        if (ch < 63) {
            #pragma unroll
            for (int mf = 0; mf < 2; ++mf) {
                #pragma unroll
                for (int j = 0; j < 2; ++j)
                    af[mf][j] = an2[mf][j];
                sqv[mf] = sqn[mf];
            }
        }
    }

    // ---- argmin reduce + ||z||^2 + loss partial ----
    float* redv = (float*)(smem + 24576);          // [2][64]
    int*   redi = (int*)(smem + 25088);            // [2][64]
    float* zsqa = (float*)(smem + 25600);          // [64]

    #pragma unroll
    for (int nf = 0; nf < 2; ++nf) {
        float v_ = bv[nf]; int i_ = bi[nf];
        #pragma unroll
        for (int m = 16; m <= 32; m <<= 1) {
            float ov = __shfl_xor(v_, m);
            int oi = __shfl_xor(i_, m);
            if (ov < v_ || (ov == v_ && oi < i_)) { v_ = ov; i_ = oi; }
        }
        if (g == 0) {
            int rl = wn * 32 + nf * 16 + c15;
            redv[wm * 64 + rl] = v_;
            redi[wm * 64 + rl] = i_;
        }
    }
    if (wm == 0) {
        #pragma unroll
        for (int nf = 0; nf < 2; ++nf) {
            float s = 0.f;
            #pragma unroll
            for (int j = 0; j < 2; ++j)
                #pragma unroll
                for (int e = 0; e < 8; ++e) {
                    float zv = (float)zfh[j][nf][e];
                    s += zv * zv;
                }
            s += __shfl_xor(s, 16);
            s += __shfl_xor(s, 32);
            if (g == 0) zsqa[wn * 32 + nf * 16 + c15] = s;
        }
    }
    __syncthreads();
    if (tid < 64) {
        float v0 = redv[tid]; int i0 = redi[tid];
        float v1 = redv[64 + tid]; int i1 = redi[64 + tid];
        if (v1 < v0 || (v1 == v0 && i1 < i0)) { v0 = v1; i0 = i1; }
        int grow = row0 + tid;
        idx[grow] = i0;
        out_idx[grow] = (float)i0;
        atomicAdd(&counts[i0], 1);
        float lossv = v0 + zsqa[tid];
        #pragma unroll
        for (int m = 1; m < 64; m <<= 1) lossv += __shfl_xor(lossv, m);
        if (tid == 0) lpart[blockIdx.x] = lossv;
    }
}

// ---------------------------------------------------------------------------
// k_recv: x[row] = Ee[idx[row]] @ WrT + b_recv  (single-pass f16 MFMA).
// Blocks 0..511: 64 rows each, 16 col-chunks of 64 (B dbuf 2x8KB).
// Block 512: final scalars (losses + entropy).
__global__ __launch_bounds__(256) void k_recv(const _Float16* __restrict__ Ee,
                                              const _Float16* __restrict__ WrT,
                                              const float* __restrict__ br,
                                              const int* __restrict__ idx,
                                              const int* __restrict__ counts,
                                              const float* __restrict__ lpart,
                                              float* __restrict__ x,
                                              float* __restrict__ out_sc) {
    __shared__ char smem[24832];
    int tid = threadIdx.x;

    if (blockIdx.x == 512) {
        float* red = (float*)smem;
        red[tid] = lpart[tid] + lpart[256 + tid];
        __syncthreads();
        for (int s = 128; s > 0; s >>= 1) {
            if (tid < s) red[tid] += red[tid + s];
            __syncthreads();
        }
        float loss = red[0];
        __syncthreads();
        float ep = 0.f;
        for (int k = tid; k < KC; k += 256) {
            int c = counts[k];
            if (c > 0) {
                float p = (float)c / 32768.0f;
                ep += p * logf(p);
            }
        }
        red[tid] = ep; __syncthreads();
        for (int s = 128; s > 0; s >>= 1) {
            if (tid < s) red[tid] += red[tid + s];
            __syncthreads();
        }
        if (tid == 0) {
            out_sc[0] = loss;
            out_sc[1] = loss;
            out_sc[2] = -red[0] * 1.4426950408889634f;
        }
        return;
    }

    const int row0 = blockIdx.x * 64;
    const int wid = tid >> 6, lane = tid & 63;
    const int c15 = lane & 15, g = lane >> 4;
    const int g16 = g * 16;
    int* sidx = (int*)(smem + 24576);

    if (tid < 64) sidx[tid] = idx[row0 + tid];
    __syncthreads();

    // stage A: gathered code rows [64][128B], swizzled source
    #pragma unroll
    for (int t = 0; t < 2; ++t) {
        int p = t * 4096 + tid * 16;
        int r = p >> 7, off = p & 127;
        gll16((const char*)Ee + (size_t)sidx[r] * 128 + (off ^ ((r & 7) << 4)),
              smem + p);
    }

    auto stageW = [&](int cc, int buf) {     // WrT col-chunk [64][128B]
        char* dst = smem + 8192 + buf * 8192;
        #pragma unroll
        for (int t = 0; t < 2; ++t) {
            int p = t * 4096 + tid * 16;
            int r = p >> 7, off = p & 127;
            gll16((const char*)WrT + (size_t)(cc * 64 + r) * 128
                      + (off ^ ((r & 7) << 4)),
                  dst + p);
        }
    };
    stageW(0, 0);
    __syncthreads();

    int abase[4], ax[4];
    #pragma unroll
    for (int mf = 0; mf < 4; ++mf) {
        int r = mf * 16 + c15;
        abase[mf] = r * 128;
        ax[mf] = (r & 7) << 4;
    }
    const int brow = wid * 16 + c15;
    const int bbase = 8192 + brow * 128;
    const int bx = (brow & 7) << 4;

    const f32x4 zz4 = {0.f, 0.f, 0.f, 0.f};
    for (int cc = 0; cc < 16; ++cc) {
        const int buf = cc & 1;
        if (cc < 15) stageW(cc + 1, buf ^ 1);

        const int col = cc * 64 + wid * 16 + c15;
        float bias = br[col];

        f32x4 acc[4];
        #pragma unroll
        for (int j = 0; j < 2; ++j) {
            const int kbyte = j * 64 + g16;
            f16x8 bf = *(const f16x8*)(smem + buf * 8192 + bbase + (kbyte ^ bx));
            #pragma unroll
            for (int mf = 0; mf < 4; ++mf) {
                f16x8 af = *(const f16x8*)(smem + abase[mf] + (kbyte ^ ax[mf]));
                acc[mf] = __builtin_amdgcn_mfma_f32_16x16x32_f16(
                    af, bf, j == 0 ? zz4 : acc[mf], 0, 0, 0);
            }
        }

        #pragma unroll
        for (int mf = 0; mf < 4; ++mf)
            #pragma unroll
            for (int r2 = 0; r2 < 4; ++r2)
                x[(size_t)(row0 + mf * 16 + g * 4 + r2) * DIN + col]
                    = acc[mf][r2] + bias;

        __syncthreads();
    }
}

// ---------------------------------------------------------------------------
extern "C" void kernel_launch(void* const* d_in, const int* in_sizes, int n_in,
                              void* d_out, int out_size, void* d_ws, size_t ws_size,
                              hipStream_t stream) {
    (void)in_sizes; (void)n_in; (void)out_size; (void)ws_size;
    const float* input  = (const float*)d_in[0];
    const float* W_send = (const float*)d_in[1];
    const float* b_send = (const float*)d_in[2];
    const float* emb    = (const float*)d_in[3];
    const float* W_recv = (const float*)d_in[4];
    const float* b_recv = (const float*)d_in[5];
    float* out = (float*)d_out;

    char* ws = (char*)d_ws;
    _Float16* Ee  = (_Float16*)(ws);                  // 512 KB [4096][64]
    float*    sqr = (float*)(ws + 524288);            // 16 KB
    int*      idx = (int*)  (ws + 540672);            // 128 KB
    int*   counts = (int*)  (ws + 671744);            // 16 KB
    float* lpart  = (float*)(ws + 688128);            //  2 KB (512 floats)
    _Float16* Wh  = (_Float16*)(ws + 690176);         // 128 KB [64][1024]
    _Float16* WrT = (_Float16*)(ws + 821248);         // 128 KB [1024][64]

    float* out_x   = out;                    // 33554432
    float* out_idx = out + 33554432;         // 32768
    float* out_sc  = out + 33587200;         // 3

    k_prep<<<1056, 256, 0, stream>>>(emb, W_send, W_recv, Ee, sqr, Wh, WrT, counts);
    k_main<<<512, 256, 0, stream>>>(input, Wh, b_send, Ee, sqr,
                                    idx, out_idx, counts, lpart);
    k_recv<<<513, 256, 0, stream>>>(Ee, WrT, b_recv, idx, counts, lpart,
                                    out_x, out_sc);
}

// Round 18
// 90.456 us; speedup vs baseline: 1.2917x; 1.2917x over previous
//
#include <hip/hip_runtime.h>

#define DIN 1024
#define DC 64
#define KC 4096

typedef _Float16 f16x8 __attribute__((ext_vector_type(8)));
typedef _Float16 f16x4 __attribute__((ext_vector_type(4)));
typedef float f32x4 __attribute__((ext_vector_type(4)));

__device__ __forceinline__ void gll16(const void* g, void* l) {
    __builtin_amdgcn_global_load_lds(
        (const __attribute__((address_space(1))) unsigned int*)g,
        (__attribute__((address_space(3))) unsigned int*)l, 16, 0, 0);
}

// ---------------------------------------------------------------------------
// Prep.  b<1024: Ee [4096][64] f16 + sqr fp32 + zero counts.
//        b<1040: W_send -> Wh [64 col][1024 k] f16 (transposed).
//        b<1056: W_recv -> WrT [1024 col][64 k] f16 (transposed).
__global__ __launch_bounds__(256) void k_prep(const float* __restrict__ emb,
                                              const float* __restrict__ Ws,
                                              const float* __restrict__ Wr,
                                              _Float16* __restrict__ Ee,
                                              float* __restrict__ sqr,
                                              _Float16* __restrict__ Wh,
                                              _Float16* __restrict__ WrT,
                                              int* __restrict__ counts) {
    int b = blockIdx.x;
    int tid = threadIdx.x;
    if (b < 1024) {
        int code = b * 4 + (tid >> 6);
        int lane = tid & 63;
        float v = emb[(size_t)code * DC + lane];
        Ee[(size_t)code * 64 + lane] = (_Float16)v;
        float s = v * v;
        #pragma unroll
        for (int m = 1; m < 64; m <<= 1) s += __shfl_xor(s, m);
        if (lane == 0) sqr[code] = s;
        if (tid < 4) counts[b * 4 + tid] = 0;
        return;
    }
    if (b < 1040) {
        int k0 = (b - 1024) * 64;
        #pragma unroll
        for (int it = 0; it < 16; ++it) {
            int q = it * 256 + tid;          // 4096 = 64c x 64k
            int c = q >> 6, kl = q & 63;
            float v = Ws[(size_t)(k0 + kl) * 64 + c];
            Wh[(size_t)c * 1024 + k0 + kl] = (_Float16)v;
        }
        return;
    }
    // WrT[col][k] = W_recv[k][col], coalesced reads
    int b2 = b - 1040;
    #pragma unroll
    for (int it = 0; it < 16; ++it) {
        int k = it * 4 + (tid >> 6);
        int rr = b2 * 64 + (tid & 63);
        WrT[(size_t)rr * 64 + k] = (_Float16)Wr[(size_t)k * 1024 + rr];
    }
}

// ---------------------------------------------------------------------------
// Fused send + score (R11 structure; score chunk 64->128 codes).
// 256 thr, 64 rows/block, grid 512.
// Send: z = in @ W_send + b (f16 MFMA, 16 K-steps, dbuf 2x16KB @[0,32K)).
// Zt: acc+bias -> f16 -> swizzled Zt[64][128B] @32768 (own region).
// Score: 32 chunks x 128 codes (E dbuf 2x16KB @[0,32K), gll16) + loss.
__global__ __launch_bounds__(256) void k_main(const float* __restrict__ in,
                                              const _Float16* __restrict__ Wh,
                                              const float* __restrict__ bs,
                                              const _Float16* __restrict__ Ee,
                                              const float* __restrict__ sqr,
                                              int* __restrict__ idx,
                                              float* __restrict__ out_idx,
                                              int* __restrict__ counts,
                                              float* __restrict__ lpart) {
    __shared__ char smem[42240];
    const int tid = threadIdx.x;
    const int row0 = blockIdx.x * 64;
    const int wid = tid >> 6, lane = tid & 63;
    const int c15 = lane & 15, g = lane >> 4;
    const int g16 = g * 16;
    const int wm = wid >> 1, wn = wid & 1;
    const f32x4 zz4 = {0.f, 0.f, 0.f, 0.f};

    // ================= send phase =================
    f32x4 acc[2][2];
    #pragma unroll
    for (int mf = 0; mf < 2; ++mf)
        #pragma unroll
        for (int nf = 0; nf < 2; ++nf) acc[mf][nf] = zz4;

    int abyte[2], aswz[2], bbyte[2], bswz[2];
    #pragma unroll
    for (int mf = 0; mf < 2; ++mf) {
        int r = wm * 32 + mf * 16 + c15;
        abyte[mf] = r * 128; aswz[mf] = (r & 7) << 4;
    }
    #pragma unroll
    for (int nf = 0; nf < 2; ++nf) {
        int c = wn * 32 + nf * 16 + c15;
        bbyte[nf] = c * 128; bswz[nf] = (c & 7) << 4;
    }

    auto stageB = [&](int buf, int s) {      // Wh k-chunk: 64 cols x 128 B
        char* dst = smem + buf * 16384 + 8192;
        #pragma unroll
        for (int r = 0; r < 2; ++r) {
            int p = r * 4096 + wid * 1024 + lane * 16;
            int row = p >> 7, off = p & 127;
            int soff = off ^ ((row & 7) << 4);
            gll16((const char*)Wh + (size_t)row * 2048 + s * 128 + soff,
                  dst + p);
        }
    };
    auto loadA = [&](int s, float4* a) {
        #pragma unroll
        for (int it = 0; it < 4; ++it) {
            int q = it * 256 + tid;
            int r = q >> 4, c4 = q & 15;
            a[it] = *(const float4*)&in[(size_t)(row0 + r) * DIN + s * 64 + c4 * 4];
        }
    };
    auto writeA = [&](int buf, const float4* a) {
        char* Ah = smem + buf * 16384;
        #pragma unroll
        for (int it = 0; it < 4; ++it) {
            int q = it * 256 + tid;
            int r = q >> 4, c4 = q & 15;
            float v[4] = {a[it].x, a[it].y, a[it].z, a[it].w};
            f16x4 h;
            #pragma unroll
            for (int j = 0; j < 4; ++j) h[j] = (_Float16)v[j];
            int o = r * 128 + ((c4 * 8) ^ ((r & 7) << 4));
            *(f16x4*)(Ah + o) = h;
        }
    };
    auto computeS = [&](int buf) {
        const char* Ah = smem + buf * 16384;
        const char* Bh = Ah + 8192;
        #pragma unroll
        for (int ks = 0; ks < 2; ++ks) {
            int koff = ks * 64 + g16;
            f16x8 bh[2];
            #pragma unroll
            for (int nf = 0; nf < 2; ++nf)
                bh[nf] = *(const f16x8*)(Bh + bbyte[nf] + (koff ^ bswz[nf]));
            #pragma unroll
            for (int mf = 0; mf < 2; ++mf) {
                f16x8 ah = *(const f16x8*)(Ah + abyte[mf] + (koff ^ aswz[mf]));
                #pragma unroll
                for (int nf = 0; nf < 2; ++nf)
                    acc[mf][nf] = __builtin_amdgcn_mfma_f32_16x16x32_f16(
                        ah, bh[nf], acc[mf][nf], 0, 0, 0);
            }
        }
    };

    {
        float4 a0[4];
        loadA(0, a0);
        stageB(0, 0);
        writeA(0, a0);
    }
    __syncthreads();
    for (int s = 0; s < 16; ++s) {
        int c = s & 1;
        float4 an[4];
        if (s < 15) {
            loadA(s + 1, an);
            stageB(c ^ 1, s + 1);
        }
        computeS(c);
        if (s < 15) writeA(c ^ 1, an);
        __syncthreads();
    }

    // ================= z -> Zt (LDS, f16, swizzled) @32768 =================
    char* Zt = smem + 32768;
    #pragma unroll
    for (int nf = 0; nf < 2; ++nf) {
        int k = wn * 32 + nf * 16 + c15;
        float bias = bs[k];
        #pragma unroll
        for (int mf = 0; mf < 2; ++mf)
            #pragma unroll
            for (int r2 = 0; r2 < 4; ++r2) {
                int row = wm * 32 + mf * 16 + g * 4 + r2;
                *(_Float16*)(Zt + row * 128 + ((k * 2) ^ ((row & 7) << 4)))
                    = (_Float16)(acc[mf][nf][r2] + bias);
            }
    }

    auto stageE = [&](int ch, int buf) {     // 128 codes x 128 B = 16 KB
        char* dst = smem + buf * 16384;
        const char* src = (const char*)Ee + (size_t)ch * 16384;
        #pragma unroll
        for (int t = 0; t < 4; ++t) {
            int p = t * 4096 + tid * 16;
            int r = p >> 7, off = p & 127;
            gll16(src + r * 128 + (off ^ ((r & 7) << 4)), dst + p);
        }
    };
    stageE(0, 0);      // buf0 last read at s=14; safe after final barrier
    __syncthreads();   // Zt visible, E chunk 0 loaded

    // ================= score phase (32 chunks of 128) =================
    // wm (0..1): codes wm*64 + mf*16, mf<4 ; wn (0..1): rows wn*32.
    f16x8 zfh[2][2];
    #pragma unroll
    for (int nf = 0; nf < 2; ++nf) {
        int zr = wn * 32 + nf * 16 + c15;
        int sw = (zr & 7) << 4;
        #pragma unroll
        for (int j = 0; j < 2; ++j)
            zfh[j][nf] = *(const f16x8*)(Zt + zr * 128 + ((j * 64 + g16) ^ sw));
    }

    int rbase[4], rx[4];
    #pragma unroll
    for (int mf = 0; mf < 4; ++mf) {
        int r = wm * 64 + mf * 16 + c15;
        rbase[mf] = r * 128;
        rx[mf] = (r & 7) << 4;
    }

    float bv[2];
    int   bi[2];
    #pragma unroll
    for (int nf = 0; nf < 2; ++nf) { bv[nf] = 3.402823466e38f; bi[nf] = 0; }

    for (int ch = 0; ch < 32; ++ch) {
        const int buf = ch & 1;
        f32x4 sqv[4];
        #pragma unroll
        for (int mf = 0; mf < 4; ++mf)
            sqv[mf] = *(const f32x4*)(sqr + ch * 128 + wm * 64 + mf * 16 + g * 4);

        if (ch < 31) stageE(ch + 1, buf ^ 1);

        const char* base = smem + buf * 16384;
        f32x4 sacc[4][2];
        #pragma unroll
        for (int j = 0; j < 2; ++j) {
            const int kbyte = j * 64 + g16;
            f16x8 af[4];
            #pragma unroll
            for (int mf = 0; mf < 4; ++mf)
                af[mf] = *(const f16x8*)(base + rbase[mf] + (kbyte ^ rx[mf]));
            #pragma unroll
            for (int mf = 0; mf < 4; ++mf)
                #pragma unroll
                for (int nf = 0; nf < 2; ++nf)
                    sacc[mf][nf] = __builtin_amdgcn_mfma_f32_16x16x32_f16(
                        af[mf], zfh[j][nf],
                        j == 0 ? zz4 : sacc[mf][nf], 0, 0, 0);
        }

        #pragma unroll
        for (int nf = 0; nf < 2; ++nf) {
            #pragma unroll
            for (int mf = 0; mf < 4; ++mf) {
                f32x4 v = sqv[mf] - sacc[mf][nf] * 2.0f;
                #pragma unroll
                for (int r2 = 0; r2 < 4; ++r2) {
                    if (v[r2] < bv[nf]) {
                        bv[nf] = v[r2];
                        bi[nf] = ch * 128 + wm * 64 + mf * 16 + g * 4 + r2;
                    }
                }
            }
        }
        __syncthreads();
    }

    // ---- argmin reduce + ||z||^2 + loss partial ----
    float* redv = (float*)(smem + 40960);          // [2][64]
    int*   redi = (int*)(smem + 41472);            // [2][64]
    float* zsqa = (float*)(smem + 41984);          // [64]

    #pragma unroll
    for (int nf = 0; nf < 2; ++nf) {
        float v_ = bv[nf]; int i_ = bi[nf];
        #pragma unroll
        for (int m = 16; m <= 32; m <<= 1) {
            float ov = __shfl_xor(v_, m);
            int oi = __shfl_xor(i_, m);
            if (ov < v_ || (ov == v_ && oi < i_)) { v_ = ov; i_ = oi; }
        }
        if (g == 0) {
            int rl = wn * 32 + nf * 16 + c15;
            redv[wm * 64 + rl] = v_;
            redi[wm * 64 + rl] = i_;
        }
    }
    if (wm == 0) {
        #pragma unroll
        for (int nf = 0; nf < 2; ++nf) {
            float s = 0.f;
            #pragma unroll
            for (int j = 0; j < 2; ++j)
                #pragma unroll
                for (int e = 0; e < 8; ++e) {
                    float zv = (float)zfh[j][nf][e];
                    s += zv * zv;
                }
            s += __shfl_xor(s, 16);
            s += __shfl_xor(s, 32);
            if (g == 0) zsqa[wn * 32 + nf * 16 + c15] = s;
        }
    }
    __syncthreads();
    if (tid < 64) {
        float v0 = redv[tid]; int i0 = redi[tid];
        float v1 = redv[64 + tid]; int i1 = redi[64 + tid];
        if (v1 < v0 || (v1 == v0 && i1 < i0)) { v0 = v1; i0 = i1; }
        int grow = row0 + tid;
        idx[grow] = i0;
        out_idx[grow] = (float)i0;
        atomicAdd(&counts[i0], 1);
        float lossv = v0 + zsqa[tid];
        #pragma unroll
        for (int m = 1; m < 64; m <<= 1) lossv += __shfl_xor(lossv, m);
        if (tid == 0) lpart[blockIdx.x] = lossv;
    }
}

// ---------------------------------------------------------------------------
// k_recv: x[row] = Ee[idx[row]] @ WrT + b_recv  (single-pass f16 MFMA).
// Blocks 0..511: 64 rows each, 16 col-chunks of 64 (B dbuf 2x8KB).
// Block 512: final scalars (losses + entropy).
__global__ __launch_bounds__(256) void k_recv(const _Float16* __restrict__ Ee,
                                              const _Float16* __restrict__ WrT,
                                              const float* __restrict__ br,
                                              const int* __restrict__ idx,
                                              const int* __restrict__ counts,
                                              const float* __restrict__ lpart,
                                              float* __restrict__ x,
                                              float* __restrict__ out_sc) {
    __shared__ char smem[24832];
    int tid = threadIdx.x;

    if (blockIdx.x == 512) {
        float* red = (float*)smem;
        red[tid] = lpart[tid] + lpart[256 + tid];
        __syncthreads();
        for (int s = 128; s > 0; s >>= 1) {
            if (tid < s) red[tid] += red[tid + s];
            __syncthreads();
        }
        float loss = red[0];
        __syncthreads();
        float ep = 0.f;
        for (int k = tid; k < KC; k += 256) {
            int c = counts[k];
            if (c > 0) {
                float p = (float)c / 32768.0f;
                ep += p * logf(p);
            }
        }
        red[tid] = ep; __syncthreads();
        for (int s = 128; s > 0; s >>= 1) {
            if (tid < s) red[tid] += red[tid + s];
            __syncthreads();
        }
        if (tid == 0) {
            out_sc[0] = loss;
            out_sc[1] = loss;
            out_sc[2] = -red[0] * 1.4426950408889634f;
        }
        return;
    }

    const int row0 = blockIdx.x * 64;
    const int wid = tid >> 6, lane = tid & 63;
    const int c15 = lane & 15, g = lane >> 4;
    const int g16 = g * 16;
    int* sidx = (int*)(smem + 24576);

    if (tid < 64) sidx[tid] = idx[row0 + tid];
    __syncthreads();

    // stage A: gathered code rows [64][128B], swizzled source
    #pragma unroll
    for (int t = 0; t < 2; ++t) {
        int p = t * 4096 + tid * 16;
        int r = p >> 7, off = p & 127;
        gll16((const char*)Ee + (size_t)sidx[r] * 128 + (off ^ ((r & 7) << 4)),
              smem + p);
    }

    auto stageW = [&](int cc, int buf) {     // WrT col-chunk [64][128B]
        char* dst = smem + 8192 + buf * 8192;
        #pragma unroll
        for (int t = 0; t < 2; ++t) {
            int p = t * 4096 + tid * 16;
            int r = p >> 7, off = p & 127;
            gll16((const char*)WrT + (size_t)(cc * 64 + r) * 128
                      + (off ^ ((r & 7) << 4)),
                  dst + p);
        }
    };
    stageW(0, 0);
    __syncthreads();

    int abase[4], ax[4];
    #pragma unroll
    for (int mf = 0; mf < 4; ++mf) {
        int r = mf * 16 + c15;
        abase[mf] = r * 128;
        ax[mf] = (r & 7) << 4;
    }
    const int brow = wid * 16 + c15;
    const int bbase = 8192 + brow * 128;
    const int bx = (brow & 7) << 4;

    const f32x4 zz4 = {0.f, 0.f, 0.f, 0.f};
    for (int cc = 0; cc < 16; ++cc) {
        const int buf = cc & 1;
        if (cc < 15) stageW(cc + 1, buf ^ 1);

        const int col = cc * 64 + wid * 16 + c15;
        float bias = br[col];

        f32x4 acc[4];
        #pragma unroll
        for (int j = 0; j < 2; ++j) {
            const int kbyte = j * 64 + g16;
            f16x8 bf = *(const f16x8*)(smem + buf * 8192 + bbase + (kbyte ^ bx));
            #pragma unroll
            for (int mf = 0; mf < 4; ++mf) {
                f16x8 af = *(const f16x8*)(smem + abase[mf] + (kbyte ^ ax[mf]));
                acc[mf] = __builtin_amdgcn_mfma_f32_16x16x32_f16(
                    af, bf, j == 0 ? zz4 : acc[mf], 0, 0, 0);
            }
        }

        #pragma unroll
        for (int mf = 0; mf < 4; ++mf)
            #pragma unroll
            for (int r2 = 0; r2 < 4; ++r2)
                x[(size_t)(row0 + mf * 16 + g * 4 + r2) * DIN + col]
                    = acc[mf][r2] + bias;

        __syncthreads();
    }
}

// ---------------------------------------------------------------------------
extern "C" void kernel_launch(void* const* d_in, const int* in_sizes, int n_in,
                              void* d_out, int out_size, void* d_ws, size_t ws_size,
                              hipStream_t stream) {
    (void)in_sizes; (void)n_in; (void)out_size; (void)ws_size;
    const float* input  = (const float*)d_in[0];
    const float* W_send = (const float*)d_in[1];
    const float* b_send = (const float*)d_in[2];
    const float* emb    = (const float*)d_in[3];
    const float* W_recv = (const float*)d_in[4];
    const float* b_recv = (const float*)d_in[5];
    float* out = (float*)d_out;

    char* ws = (char*)d_ws;
    _Float16* Ee  = (_Float16*)(ws);                  // 512 KB [4096][64]
    float*    sqr = (float*)(ws + 524288);            // 16 KB
    int*      idx = (int*)  (ws + 540672);            // 128 KB
    int*   counts = (int*)  (ws + 671744);            // 16 KB
    float* lpart  = (float*)(ws + 688128);            //  2 KB (512 floats)
    _Float16* Wh  = (_Float16*)(ws + 690176);         // 128 KB [64][1024]
    _Float16* WrT = (_Float16*)(ws + 821248);         // 128 KB [1024][64]

    float* out_x   = out;                    // 33554432
    float* out_idx = out + 33554432;         // 32768
    float* out_sc  = out + 33587200;         // 3

    k_prep<<<1056, 256, 0, stream>>>(emb, W_send, W_recv, Ee, sqr, Wh, WrT, counts);
    k_main<<<512, 256, 0, stream>>>(input, Wh, b_send, Ee, sqr,
                                    idx, out_idx, counts, lpart);
    k_recv<<<513, 256, 0, stream>>>(Ee, WrT, b_recv, idx, counts, lpart,
                                    out_x, out_sc);
}